// Round 1
// baseline (1147.797 us; speedup 1.0000x reference)
//
#include <hip/hip_runtime.h>

// Transformer block, MI355X. See theory: attention factorizes to A[n,qh,s]*Vs[n,s,d].
// 6 bf16-MFMA GEMMs (m97-style 128x128 tile, BK=32, global_load_lds w=16) + small fused kernels.
// Workspace layout: 366 MB total (assumes ws_size >= 384 MB).

#define S_LEN 4096
#define EMB   1024
#define NBATCH 4
#define NH    16
#define HD    64
#define DFF   4096
#define MROWS (NBATCH * S_LEN)  // 16384

typedef __attribute__((ext_vector_type(8))) short s16x8;
typedef __attribute__((ext_vector_type(4))) float f32x4;

__device__ __forceinline__ float uas_f(unsigned u) { union { unsigned u; float f; } c; c.u = u; return c.f; }
__device__ __forceinline__ unsigned fas_u(float f) { union { float f; unsigned u; } c; c.f = f; return c.u; }
__device__ __forceinline__ short f2bf(float f) {
  unsigned u = fas_u(f);
  u += 0x7fffu + ((u >> 16) & 1u);           // RNE
  return (short)(unsigned short)(u >> 16);
}
__device__ __forceinline__ float bf2f(short h) { return uas_f(((unsigned)(unsigned short)h) << 16); }
__device__ __forceinline__ float bflo(unsigned pk) { return uas_f(pk << 16); }
__device__ __forceinline__ float bfhi(unsigned pk) { return uas_f(pk & 0xffff0000u); }

__device__ __forceinline__ void gld16(const short* g, short* l) {
  __builtin_amdgcn_global_load_lds((const __attribute__((address_space(1))) void*)g,
                                   (__attribute__((address_space(3))) void*)l, 16, 0, 0);
}

// ---------------- GEMM: C[M,N] = A[M,K] @ B[K,N], A row-major bf16, BT = B^T [N,K] bf16 -------------
// 128x128 tile, BK=32, 4 waves (2x2), each wave 4x4 frags of 16x16x32.
template<bool OBF, bool RELU, bool BIAS>
__global__ __launch_bounds__(256) void gemm_k(const short* __restrict__ A,
                                              const short* __restrict__ BT,
                                              const float* __restrict__ bias,
                                              void* __restrict__ Cp,
                                              int M, int N, int K) {
  __shared__ __align__(16) short As[128 * 32];
  __shared__ __align__(16) short Bs[128 * 32];
  const int t = threadIdx.x;
  const int lane = t & 63;
  const int wave = t >> 6;
  const int wm = wave >> 1, wn = wave & 1;
  const size_t m0 = (size_t)blockIdx.y * 128, n0 = (size_t)blockIdx.x * 128;

  const int f0 = t, f1 = t + 256;  // staging: flat chunk id; LDS byte = flat*16 (linear; required by global_load_lds)
  const size_t ga0 = (m0 + (size_t)(f0 >> 2)) * K + ((f0 & 3) << 3);
  const size_t ga1 = (m0 + (size_t)(f1 >> 2)) * K + ((f1 & 3) << 3);
  const size_t gb0 = (n0 + (size_t)(f0 >> 2)) * K + ((f0 & 3) << 3);
  const size_t gb1 = (n0 + (size_t)(f1 >> 2)) * K + ((f1 & 3) << 3);

  f32x4 acc[4][4] = {};
  const int kg = (lane >> 4) << 3;          // K sub-slot (identical for A and B frags -> perm cancels)
  const int arow = wm * 64 + (lane & 15);
  const int brow = wn * 64 + (lane & 15);

  for (int k0 = 0; k0 < K; k0 += 32) {
    gld16(A + ga0 + k0, &As[f0 * 8]);
    gld16(A + ga1 + k0, &As[f1 * 8]);
    gld16(BT + gb0 + k0, &Bs[f0 * 8]);
    gld16(BT + gb1 + k0, &Bs[f1 * 8]);
    __syncthreads();   // drains vmcnt -> LDS valid
    s16x8 af[4], bfr[4];
#pragma unroll
    for (int i = 0; i < 4; ++i) {
      af[i]  = *(const s16x8*)&As[(arow + i * 16) * 32 + kg];
      bfr[i] = *(const s16x8*)&Bs[(brow + i * 16) * 32 + kg];
    }
#pragma unroll
    for (int i = 0; i < 4; ++i)
#pragma unroll
      for (int j = 0; j < 4; ++j)
        acc[i][j] = __builtin_amdgcn_mfma_f32_16x16x32_bf16(af[i], bfr[j], acc[i][j], 0, 0, 0);
    __syncthreads();
  }

  // C/D layout (HW-verified): col = lane&15, row = (lane>>4)*4 + reg
  const int r0 = (lane >> 4) << 2;
  const int c0 = lane & 15;
#pragma unroll
  for (int i = 0; i < 4; ++i) {
#pragma unroll
    for (int j = 0; j < 4; ++j) {
      const size_t row = m0 + (size_t)(wm * 64 + i * 16 + r0);
      const size_t col = n0 + (size_t)(wn * 64 + j * 16 + c0);
      float bv = 0.f;
      if (BIAS) bv = bias[col];
#pragma unroll
      for (int r = 0; r < 4; ++r) {
        float v = acc[i][j][r] + bv;
        if (RELU) v = fmaxf(v, 0.f);
        if (OBF) ((short*)Cp)[(row + r) * N + col] = f2bf(v);
        else     ((float*)Cp)[(row + r) * N + col] = v;
      }
    }
  }
}

// ---------------- fp32 -> bf16 convert (x) ----------------
__global__ __launch_bounds__(256) void cvtx_k(const float* __restrict__ in, short* __restrict__ out) {
  const size_t i = ((size_t)blockIdx.x * 256 + threadIdx.x) * 8;
  const float4 a = *(const float4*)(in + i);
  const float4 b = *(const float4*)(in + i + 4);
  s16x8 o;
  o[0] = f2bf(a.x); o[1] = f2bf(a.y); o[2] = f2bf(a.z); o[3] = f2bf(a.w);
  o[4] = f2bf(b.x); o[5] = f2bf(b.y); o[6] = f2bf(b.z); o[7] = f2bf(b.w);
  *(s16x8*)(out + i) = o;
}

// ---------------- W[K,N] fp32 -> W^T[N,K] bf16 ----------------
__global__ void transpose_cvt_k(const float* __restrict__ W, short* __restrict__ WT, int K, int N) {
  __shared__ float tile[32][33];
  const int tx = threadIdx.x, ty = threadIdx.y;  // (32,8)
  const int n0 = blockIdx.x * 32, k0 = blockIdx.y * 32;
#pragma unroll
  for (int i = 0; i < 32; i += 8)
    tile[ty + i][tx] = W[(size_t)(k0 + ty + i) * N + n0 + tx];
  __syncthreads();
#pragma unroll
  for (int i = 0; i < 32; i += 8)
    WT[(size_t)(n0 + ty + i) * K + k0 + tx] = f2bf(tile[tx][ty + i]);
}

// ---------------- energy[n,qh,kh,s] = (1/8) sum_d q[n,s,qh*64+d]*k[n,s,kh*64+d] ----------------
__global__ __launch_bounds__(256) void energy_k(const short* __restrict__ q,
                                                const short* __restrict__ k,
                                                float* __restrict__ E) {
  __shared__ short qs[8][1024];
  __shared__ short ks[8][1024];
  const int t = threadIdx.x;
  const int blk = blockIdx.x;          // 2048 blocks, 8 seq positions each
  const int n = blk >> 9;
  const int s0 = (blk & 511) << 3;
  const size_t base = ((size_t)n * S_LEN + s0) * EMB;
#pragma unroll
  for (int i = 0; i < 4; ++i) {
    int idx = (t + i * 256) * 8;
    *(s16x8*)&qs[0][idx] = *(const s16x8*)&q[base + idx];
    *(s16x8*)&ks[0][idx] = *(const s16x8*)&k[base + idx];
  }
  __syncthreads();
  const int qh = t >> 4, kh = t & 15;
  const unsigned* qb = (const unsigned*)&qs[0][0] + qh * 32;
  const unsigned* kb = (const unsigned*)&ks[0][0] + kh * 32;
  float e[8];
#pragma unroll
  for (int sl = 0; sl < 8; ++sl) {
    const unsigned* qrow = qb + sl * 512;
    const unsigned* krow = kb + sl * 512;
    float acc = 0.f;
#pragma unroll 8
    for (int p = 0; p < 32; ++p) {
      int pp = (p + kh) & 31;            // rotate to avoid LDS bank conflicts
      unsigned qp = qrow[pp];
      unsigned kp = krow[pp];
      acc += bflo(qp) * bflo(kp) + bfhi(qp) * bfhi(kp);
    }
    e[sl] = acc * 0.125f;                // / sqrt(64)
  }
  float* dst = E + ((size_t)((n * NH + qh) * NH + kh)) * S_LEN + s0;
#pragma unroll
  for (int sl = 0; sl < 8; ++sl) dst[sl] = e[sl];  // 32B contiguous per thread
}

// ---------------- per-row (1024 rows) max + 1/sum_exp over s=4096 ----------------
__global__ __launch_bounds__(256) void smstat_k(const float* __restrict__ E, float* __restrict__ mz) {
  __shared__ float red[8];
  const int t = threadIdx.x;
  const size_t r = blockIdx.x;
  const float* row = E + r * S_LEN;
  float vals[16];
  float m = -1e30f;
#pragma unroll
  for (int j = 0; j < 16; ++j) { vals[j] = row[t + j * 256]; m = fmaxf(m, vals[j]); }
#pragma unroll
  for (int off = 32; off > 0; off >>= 1) m = fmaxf(m, __shfl_down(m, off));
  if ((t & 63) == 0) red[t >> 6] = m;
  __syncthreads();
  m = fmaxf(fmaxf(red[0], red[1]), fmaxf(red[2], red[3]));
  float s = 0.f;
#pragma unroll
  for (int j = 0; j < 16; ++j) s += __expf(vals[j] - m);
#pragma unroll
  for (int off = 32; off > 0; off >>= 1) s += __shfl_down(s, off);
  if ((t & 63) == 0) red[4 + (t >> 6)] = s;
  __syncthreads();
  if (t == 0) {
    float Z = red[4] + red[5] + red[6] + red[7];
    mz[2 * r] = m;
    mz[2 * r + 1] = 1.f / Z;
  }
}

// ---------------- A[nq,s] = sum_kh softmax weight ----------------
__global__ __launch_bounds__(256) void asum_k(const float* __restrict__ E, const float* __restrict__ mz,
                                              float* __restrict__ A) {
  const int nq = blockIdx.y;                      // 0..63 = n*16+qh
  const int s = blockIdx.x * 256 + threadIdx.x;   // 0..4095
  float a = 0.f;
#pragma unroll
  for (int kh = 0; kh < NH; ++kh) {
    const int r = nq * NH + kh;
    a += __expf(E[(size_t)r * S_LEN + s] - mz[2 * r]) * mz[2 * r + 1];
  }
  A[(size_t)nq * S_LEN + s] = a;
}

// ---------------- Vs[n,s,d] = sum_h v[n,s,h*64+d] ----------------
__global__ __launch_bounds__(256) void vsum_k(const short* __restrict__ v, float* __restrict__ Vs) {
  const size_t i = (size_t)blockIdx.x * 256 + threadIdx.x;  // over 4*4096*64
  const size_t ns = i >> 6;
  const int d = (int)(i & 63);
  const short* p = v + ns * EMB + d;
  float a = 0.f;
#pragma unroll
  for (int h = 0; h < NH; ++h) a += bf2f(p[h * 64]);
  Vs[i] = a;
}

// ---------------- k/v output: pre[n,s,h*64+d] (bf16) -> out[n,h,s,d] (fp32) ----------------
__global__ __launch_bounds__(256) void kvout_k(const short* __restrict__ pre, float* __restrict__ out) {
  const size_t ns = blockIdx.x;
  const int n = (int)(ns >> 12), s = (int)(ns & 4095);
  const int t = threadIdx.x;
#pragma unroll
  for (int j = 0; j < 4; ++j) {
    int e = t + j * 256;
    int h = e >> 6, d = e & 63;
    out[(((size_t)n * NH + h) * S_LEN + s) * HD + d] = bf2f(pre[ns * EMB + e]);
  }
}

// ---------------- attn_in[n,s,e] = A[n, s/256, (s%256)*16 + e/64] * Vs[n, (s%256)*16+e/64, e%64] ----
__global__ __launch_bounds__(256) void attnin_k(const float* __restrict__ A, const float* __restrict__ Vs,
                                                short* __restrict__ out) {
  __shared__ float Ash[16];
  const int t = threadIdx.x;
  const size_t ns = blockIdx.x;
  const int n = (int)(ns >> 12), s = (int)(ns & 4095);
  const int qh = s >> 8;
  const int h0 = (s & 255) * 16;
  if (t < 16) Ash[t] = A[((size_t)(n * NH + qh)) * S_LEN + h0 + t];
  __syncthreads();
  const float* vsrc = Vs + ((size_t)n * S_LEN + h0) * HD;   // 1024 contiguous floats
#pragma unroll
  for (int j = 0; j < 4; ++j) {
    int e = t + j * 256;
    out[ns * EMB + e] = f2bf(Ash[e >> 6] * vsrc[e]);
  }
}

// ---------------- LayerNorm(a+b) * g + be ; optional bf16 copy ----------------
template<bool WBF>
__global__ __launch_bounds__(256) void ln_k(const float* __restrict__ a, const float* __restrict__ b,
                                            const float* __restrict__ g, const float* __restrict__ be,
                                            float* __restrict__ out, short* __restrict__ obf) {
  __shared__ float red[8];
  const int t = threadIdx.x;
  const size_t r = blockIdx.x;
  const float4 va = *(const float4*)(a + r * EMB + t * 4);
  const float4 vb = *(const float4*)(b + r * EMB + t * 4);
  const float v0 = va.x + vb.x, v1 = va.y + vb.y, v2 = va.z + vb.z, v3 = va.w + vb.w;
  float s = v0 + v1 + v2 + v3;
  float q = v0 * v0 + v1 * v1 + v2 * v2 + v3 * v3;
#pragma unroll
  for (int off = 32; off > 0; off >>= 1) { s += __shfl_down(s, off); q += __shfl_down(q, off); }
  if ((t & 63) == 0) { red[t >> 6] = s; red[4 + (t >> 6)] = q; }
  __syncthreads();
  const float S = red[0] + red[1] + red[2] + red[3];
  const float Q = red[4] + red[5] + red[6] + red[7];
  const float mu = S * (1.f / EMB);
  const float var = Q * (1.f / EMB) - mu * mu;
  const float rstd = rsqrtf(var + 1e-5f);
  const float4 vg = *(const float4*)(g + t * 4);
  const float4 ve = *(const float4*)(be + t * 4);
  const float y0 = (v0 - mu) * rstd * vg.x + ve.x;
  const float y1 = (v1 - mu) * rstd * vg.y + ve.y;
  const float y2 = (v2 - mu) * rstd * vg.z + ve.z;
  const float y3 = (v3 - mu) * rstd * vg.w + ve.w;
  float4 yo; yo.x = y0; yo.y = y1; yo.z = y2; yo.w = y3;
  *(float4*)(out + r * EMB + t * 4) = yo;
  if (WBF) {
    short4 o; o.x = f2bf(y0); o.y = f2bf(y1); o.z = f2bf(y2); o.w = f2bf(y3);
    *(short4*)(obf + r * EMB + t * 4) = o;
  }
}

extern "C" void kernel_launch(void* const* d_in, const int* in_sizes, int n_in,
                              void* d_out, int out_size, void* d_ws, size_t ws_size,
                              hipStream_t stream) {
  const float* x   = (const float*)d_in[0];
  const float* Wq  = (const float*)d_in[1];
  const float* Wk  = (const float*)d_in[2];
  const float* Wv  = (const float*)d_in[3];
  const float* Wo  = (const float*)d_in[4];
  const float* bo  = (const float*)d_in[5];
  const float* W1  = (const float*)d_in[6];
  const float* b1  = (const float*)d_in[7];
  const float* W2  = (const float*)d_in[8];
  const float* b2  = (const float*)d_in[9];
  const float* g1  = (const float*)d_in[10];
  const float* be1 = (const float*)d_in[11];
  const float* g2  = (const float*)d_in[12];
  const float* be2 = (const float*)d_in[13];

  float* y    = (float*)d_out;                       // [4,4096,1024]
  float* kout = y + (size_t)MROWS * EMB;             // [4,16,4096,64]
  float* vout = kout + (size_t)MROWS * EMB;

  constexpr size_t MB = 1ull << 20;
  char* ws = (char*)d_ws;
  short* WqT     = (short*)(ws + 0 * MB);    // 2 MB each
  short* WkT     = (short*)(ws + 2 * MB);
  short* WvT     = (short*)(ws + 4 * MB);
  short* WoT     = (short*)(ws + 6 * MB);
  short* W1T     = (short*)(ws + 8 * MB);    // 8 MB
  short* W2T     = (short*)(ws + 16 * MB);   // 8 MB
  short* xbf     = (short*)(ws + 24 * MB);   // 32 MB
  short* qpre    = (short*)(ws + 56 * MB);   // 32 MB
  short* kpre    = (short*)(ws + 88 * MB);   // 32 MB
  short* vpre    = (short*)(ws + 120 * MB);  // 32 MB
  float* energy  = (float*)(ws + 152 * MB);  // 16 MB
  float* mz      = (float*)(ws + 168 * MB);  // 8 KB
  float* Avec    = (float*)(ws + 169 * MB);  // 1 MB
  float* Vsb     = (float*)(ws + 170 * MB);  // 4 MB
  short* attn_in = (short*)(ws + 174 * MB);  // 32 MB
  float* attn_out= (float*)(ws + 206 * MB);  // 64 MB
  float* hbuf    = (float*)(ws + 270 * MB);  // 64 MB
  short* hbf     = (short*)(ws + 334 * MB);  // 32 MB
  short* ff1     = (short*)(ws + 24 * MB);   // 128 MB, reuses [24,152) (xbf/q/k/v dead)
  float* ff2     = (float*)(ws + 174 * MB);  // 64 MB, reuses [174,238) (attn_in/attn_out dead)

  // 1) casts / transposes
  cvtx_k<<<8192, 256, 0, stream>>>(x, xbf);
  transpose_cvt_k<<<dim3(32, 32),  dim3(32, 8), 0, stream>>>(Wq, WqT, EMB, EMB);
  transpose_cvt_k<<<dim3(32, 32),  dim3(32, 8), 0, stream>>>(Wk, WkT, EMB, EMB);
  transpose_cvt_k<<<dim3(32, 32),  dim3(32, 8), 0, stream>>>(Wv, WvT, EMB, EMB);
  transpose_cvt_k<<<dim3(32, 32),  dim3(32, 8), 0, stream>>>(Wo, WoT, EMB, EMB);
  transpose_cvt_k<<<dim3(128, 32), dim3(32, 8), 0, stream>>>(W1, W1T, EMB, DFF);
  transpose_cvt_k<<<dim3(32, 128), dim3(32, 8), 0, stream>>>(W2, W2T, DFF, EMB);

  // 2) projections
  gemm_k<true, false, false><<<dim3(8, 128), 256, 0, stream>>>(xbf, WqT, nullptr, qpre, MROWS, EMB, EMB);
  gemm_k<true, false, false><<<dim3(8, 128), 256, 0, stream>>>(xbf, WkT, nullptr, kpre, MROWS, EMB, EMB);
  gemm_k<true, false, false><<<dim3(8, 128), 256, 0, stream>>>(xbf, WvT, nullptr, vpre, MROWS, EMB, EMB);

  // 3) factorized "attention"
  energy_k<<<2048, 256, 0, stream>>>(qpre, kpre, energy);
  smstat_k<<<1024, 256, 0, stream>>>(energy, mz);
  asum_k<<<dim3(16, 64), 256, 0, stream>>>(energy, mz, Avec);
  vsum_k<<<4096, 256, 0, stream>>>(vpre, Vsb);
  kvout_k<<<16384, 256, 0, stream>>>(kpre, kout);
  kvout_k<<<16384, 256, 0, stream>>>(vpre, vout);
  attnin_k<<<16384, 256, 0, stream>>>(Avec, Vsb, attn_in);

  // 4) output projection + LN1
  gemm_k<false, false, true><<<dim3(8, 128), 256, 0, stream>>>(attn_in, WoT, bo, attn_out, MROWS, EMB, EMB);
  ln_k<true><<<16384, 256, 0, stream>>>(attn_out, x, g1, be1, hbuf, hbf);

  // 5) FFN + LN2
  gemm_k<true, true, true><<<dim3(32, 128), 256, 0, stream>>>(hbf, W1T, b1, ff1, MROWS, DFF, EMB);
  gemm_k<false, false, true><<<dim3(8, 128), 256, 0, stream>>>(ff1, W2T, b2, ff2, MROWS, EMB, DFF);
  ln_k<false><<<16384, 256, 0, stream>>>(ff2, hbuf, g2, be2, y, nullptr);
}

// Round 4
// 888.525 us; speedup vs baseline: 1.2918x; 1.2918x over previous
//
#include <hip/hip_runtime.h>

// Transformer block, MI355X. Attention factorizes to A[n,qh,s]*Vs[n,s,d].
// Round 4 = round 3 resubmitted verbatim (round 3 hit GPUAcquisitionTimeout; kernel never ran).
// 256x256 8-phase GEMM: stage-after-last-read phases (P2/P3, P6/P7),
// vmcnt(8) BEFORE the barrier at K-tile boundaries (cross-wave visibility), bB offset fixed.

#define S_LEN 4096
#define EMB   1024
#define NBATCH 4
#define NH    16
#define HD    64
#define DFF   4096
#define MROWS (NBATCH * S_LEN)  // 16384

typedef __attribute__((ext_vector_type(8))) short s16x8;
typedef __attribute__((ext_vector_type(4))) float f32x4;

__device__ __forceinline__ float uas_f(unsigned u) { union { unsigned u; float f; } c; c.u = u; return c.f; }
__device__ __forceinline__ unsigned fas_u(float f) { union { float f; unsigned u; } c; c.f = f; return c.u; }
__device__ __forceinline__ short f2bf(float f) {
  unsigned u = fas_u(f);
  u += 0x7fffu + ((u >> 16) & 1u);           // RNE
  return (short)(unsigned short)(u >> 16);
}
__device__ __forceinline__ float bf2f(short h) { return uas_f(((unsigned)(unsigned short)h) << 16); }
__device__ __forceinline__ float bflo(unsigned pk) { return uas_f(pk << 16); }
__device__ __forceinline__ float bfhi(unsigned pk) { return uas_f(pk & 0xffff0000u); }

__device__ __forceinline__ void gld16(const short* g, short* l) {
  __builtin_amdgcn_global_load_lds((const __attribute__((address_space(1))) void*)g,
                                   (__attribute__((address_space(3))) void*)l, 16, 0, 0);
}

// ================= 256x256 8-phase GEMM =================
// C[M,N] = A[M,K] @ BT[N,K]^T. 512 thr = 8 waves (2M x 4N), per-wave 128x64 out.
// BK=64/K-tile, 2 K-tiles/iter (8 phases). LDS 128KB: 2 bufs x (A 32K + B 32K).
// Subtile = 16 rows x 32 k (1024B), st_16x32 swizzle via pre-permuted global source.
// Sync design: every cross-wave RAW is (producer loads counted by vmcnt) -> s_barrier -> reads.
//   buf0 reads P0-P2; buf0 restage P2(B),P3(A); vmcnt(8)+BAR end of P3 covers buf1 tile.
//   buf1 reads P4-P6; buf1 restage P6(B),P7(A); vmcnt(8)+BAR end of P7 covers buf0 tile.
#define BAR()   __builtin_amdgcn_s_barrier()
#define LGKM0() asm volatile("s_waitcnt lgkmcnt(0)" ::: "memory")
#define VMC8()  asm volatile("s_waitcnt vmcnt(8)" ::: "memory")

#define LOADA(BUFOFF, QH) do { \
  _Pragma("unroll") for (int mi = 0; mi < 4; ++mi) { \
    aR[mi][0] = *(const s16x8*)(aB + (BUFOFF) + (((QH)*8 + mi*2 + 0) << 10)); \
    aR[mi][1] = *(const s16x8*)(aB + (BUFOFF) + (((QH)*8 + mi*2 + 1) << 10)); } } while (0)

#define LOADB(BUFOFF, NH_) do { \
  _Pragma("unroll") for (int nf = 0; nf < 2; ++nf) { \
    bR[NH_][nf][0] = *(const s16x8*)(bB + (BUFOFF) + ((((NH_)*2 + nf)*2 + 0) << 10)); \
    bR[NH_][nf][1] = *(const s16x8*)(bB + (BUFOFF) + ((((NH_)*2 + nf)*2 + 1) << 10)); } } while (0)

#define MFMA16(QH, NH_) do { \
  _Pragma("unroll") for (int mi = 0; mi < 4; ++mi) \
  _Pragma("unroll") for (int nf = 0; nf < 2; ++nf) { \
    acc[(QH)*4+mi][(NH_)*2+nf] = __builtin_amdgcn_mfma_f32_16x16x32_bf16(aR[mi][0], bR[NH_][nf][0], acc[(QH)*4+mi][(NH_)*2+nf], 0, 0, 0); \
    acc[(QH)*4+mi][(NH_)*2+nf] = __builtin_amdgcn_mfma_f32_16x16x32_bf16(aR[mi][1], bR[NH_][nf][1], acc[(QH)*4+mi][(NH_)*2+nf], 0, 0, 0); } } while (0)

// stage one half-tile (16 rows x 64 k per wave): 2 x gld16 (k-group subtiles 0,1)
#define STG(PTR, OPOFF, BUFOFF, H, KOFF) do { \
  const short* _s = (PTR) + (KOFF); \
  char* _d = ldsc + (BUFOFF) + (OPOFF) + (H)*16384 + wq; \
  gld16(_s, (short*)_d); gld16(_s + 32, (short*)(_d + 1024)); } while (0)

template<bool OBF, bool RELU, bool BIAS>
__global__ __launch_bounds__(512, 2) void gemm2(const short* __restrict__ A,
                                                const short* __restrict__ BT,
                                                const float* __restrict__ bias,
                                                void* __restrict__ Cp,
                                                int N, int K, int lgx) {
  __shared__ __align__(16) char lds[131072];
  char* ldsc = &lds[0];
  const int t = threadIdx.x;
  const int lane = t & 63;
  const int wave = t >> 6;
  const int wr = wave >> 2, wc = wave & 3;

  // T1: XCD-aware block swizzle (nwg % 8 == 0 for all our launches -> bijective)
  const int nwg = gridDim.x;
  const int wg = blockIdx.x;
  const int sid = (wg & 7) * (nwg >> 3) + (wg >> 3);
  const int bx = sid & ((1 << lgx) - 1);
  const int by = sid >> lgx;
  const size_t m0 = (size_t)by * 256, n0 = (size_t)bx * 256;

  // ---- staging addresses (source pre-permuted for st_16x32 swizzle; LDS dest linear) ----
  const int uc = lane ^ (((lane >> 5) & 1) << 1);      // inverse-swizzled 16B-chunk id
  const size_t arow = m0 + wave * 16 + (uc >> 2);
  const size_t brow = n0 + wave * 16 + (uc >> 2);
  const int csub = (uc & 3) << 3;
  const short* pA0 = A  + arow * K + csub;
  const short* pA1 = A  + (arow + 128) * K + csub;
  const short* pB0 = BT + brow * K + csub;
  const short* pB1 = BT + (brow + 128) * K + csub;
  const int wq = wave * 2048 + lane * 16;              // wave's 2-subtile slot + lane chunk

  // ---- ds_read bases (st_16x32 swizzle XOR on read address) ----
  int ulane = ((lane & 15) << 6) | ((lane >> 4) << 4);
  ulane ^= ((lane >> 3) & 1) << 5;
  const char* aB = ldsc + (wr << 14) + ulane;
  const char* bB = ldsc + 32768 + (wc << 13) + ulane;  // wc*8192

  s16x8 aR[4][2];
  s16x8 bR[2][2][2];
  f32x4 acc[8][4] = {};

  // ---- prologue: stage tile0 -> buf0, tile1 -> buf1; complete tile0 (16-8=8) ----
  STG(pA0, 0,     0, 0, 0);       STG(pB0, 32768, 0, 0, 0);
  STG(pB1, 32768, 0, 1, 0);       STG(pA1, 0,     0, 1, 0);
  STG(pA0, 0,     65536, 0, 64);  STG(pB0, 32768, 65536, 0, 64);
  STG(pB1, 32768, 65536, 1, 64);  STG(pA1, 0,     65536, 1, 64);
  VMC8();
  BAR();

  const int niter = K >> 7;          // 2 K-tiles (BK=64) per iteration
  for (int it = 0; it < niter; ++it) {
    const int kb = it << 7;
    int k2 = kb + 128; if (k2 > K - 64) k2 = K - 64;   // next buf0 tile (clamped tail, dead if last)
    int k3 = kb + 192; if (k3 > K - 64) k3 = K - 64;   // next buf1 tile
    // ---- P0: q(0,0) of buf0 ----
    LOADA(0, 0); LOADB(0, 0);
    BAR(); LGKM0();
    __builtin_amdgcn_s_setprio(1); MFMA16(0, 0); __builtin_amdgcn_s_setprio(0);
    BAR();
    // ---- P1: q(0,1) (last B read of buf0) ----
    LOADB(0, 1);
    BAR(); LGKM0();
    __builtin_amdgcn_s_setprio(1); MFMA16(0, 1); __builtin_amdgcn_s_setprio(0);
    BAR();
    // ---- P2: q(1,1) (last A read of buf0); restage buf0.B (safe: B last read P1) ----
    LOADA(0, 1);
    STG(pB0, 32768, 0, 0, k2); STG(pB1, 32768, 0, 1, k2);
    BAR(); LGKM0();
    __builtin_amdgcn_s_setprio(1); MFMA16(1, 1); __builtin_amdgcn_s_setprio(0);
    BAR();
    // ---- P3: q(1,0); restage buf0.A; vmcnt(8) completes buf1's tile -> BAR -> P4 reads safe ----
    STG(pA0, 0, 0, 0, k2); STG(pA1, 0, 0, 1, k2);
    VMC8();
    BAR(); LGKM0();
    __builtin_amdgcn_s_setprio(1); MFMA16(1, 0); __builtin_amdgcn_s_setprio(0);
    BAR();
    // ---- P4: q(0,0) of buf1 ----
    LOADA(65536, 0); LOADB(65536, 0);
    BAR(); LGKM0();
    __builtin_amdgcn_s_setprio(1); MFMA16(0, 0); __builtin_amdgcn_s_setprio(0);
    BAR();
    // ---- P5: q(0,1) ----
    LOADB(65536, 1);
    BAR(); LGKM0();
    __builtin_amdgcn_s_setprio(1); MFMA16(0, 1); __builtin_amdgcn_s_setprio(0);
    BAR();
    // ---- P6: q(1,1); restage buf1.B ----
    LOADA(65536, 1);
    STG(pB0, 32768, 65536, 0, k3); STG(pB1, 32768, 65536, 1, k3);
    BAR(); LGKM0();
    __builtin_amdgcn_s_setprio(1); MFMA16(1, 1); __builtin_amdgcn_s_setprio(0);
    BAR();
    // ---- P7: q(1,0); restage buf1.A; vmcnt(8) completes buf0's next tile -> BAR ----
    STG(pA0, 0, 65536, 0, k3); STG(pA1, 0, 65536, 1, k3);
    VMC8();
    BAR(); LGKM0();
    __builtin_amdgcn_s_setprio(1); MFMA16(1, 0); __builtin_amdgcn_s_setprio(0);
    BAR();
  }

  // ---- epilogue: C/D layout col=lane&15, row=(lane>>4)*4+reg ----
  const int r0 = (lane >> 4) << 2;
  const int c0 = lane & 15;
#pragma unroll
  for (int i = 0; i < 8; ++i) {
#pragma unroll
    for (int j = 0; j < 4; ++j) {
      const size_t row = m0 + (size_t)(wr * 128 + i * 16 + r0);
      const size_t col = n0 + (size_t)(wc * 64 + j * 16 + c0);
      float bv = 0.f;
      if (BIAS) bv = bias[col];
#pragma unroll
      for (int r = 0; r < 4; ++r) {
        float v = acc[i][j][r] + bv;
        if (RELU) v = fmaxf(v, 0.f);
        if (OBF) ((short*)Cp)[(row + r) * N + col] = f2bf(v);
        else     ((float*)Cp)[(row + r) * N + col] = v;
      }
    }
  }
}

// ---------------- fp32 -> bf16 convert (x) ----------------
__global__ __launch_bounds__(256) void cvtx_k(const float* __restrict__ in, short* __restrict__ out) {
  const size_t i = ((size_t)blockIdx.x * 256 + threadIdx.x) * 8;
  const float4 a = *(const float4*)(in + i);
  const float4 b = *(const float4*)(in + i + 4);
  s16x8 o;
  o[0] = f2bf(a.x); o[1] = f2bf(a.y); o[2] = f2bf(a.z); o[3] = f2bf(a.w);
  o[4] = f2bf(b.x); o[5] = f2bf(b.y); o[6] = f2bf(b.z); o[7] = f2bf(b.w);
  *(s16x8*)(out + i) = o;
}

// ---------------- W[K,N] fp32 -> W^T[N,K] bf16 ----------------
__global__ void transpose_cvt_k(const float* __restrict__ W, short* __restrict__ WT, int K, int N) {
  __shared__ float tile[32][33];
  const int tx = threadIdx.x, ty = threadIdx.y;  // (32,8)
  const int n0 = blockIdx.x * 32, k0 = blockIdx.y * 32;
#pragma unroll
  for (int i = 0; i < 32; i += 8)
    tile[ty + i][tx] = W[(size_t)(k0 + ty + i) * N + n0 + tx];
  __syncthreads();
#pragma unroll
  for (int i = 0; i < 32; i += 8)
    WT[(size_t)(n0 + ty + i) * K + k0 + tx] = f2bf(tile[tx][ty + i]);
}

// ---------------- energy[n,qh,kh,s] = (1/8) sum_d q[n,s,qh*64+d]*k[n,s,kh*64+d] ----------------
__global__ __launch_bounds__(256) void energy_k(const short* __restrict__ q,
                                                const short* __restrict__ k,
                                                float* __restrict__ E) {
  __shared__ short qs[8][1024];
  __shared__ short ks[8][1024];
  const int t = threadIdx.x;
  const int blk = blockIdx.x;          // 2048 blocks, 8 seq positions each
  const int n = blk >> 9;
  const int s0 = (blk & 511) << 3;
  const size_t base = ((size_t)n * S_LEN + s0) * EMB;
#pragma unroll
  for (int i = 0; i < 4; ++i) {
    int idx = (t + i * 256) * 8;
    *(s16x8*)&qs[0][idx] = *(const s16x8*)&q[base + idx];
    *(s16x8*)&ks[0][idx] = *(const s16x8*)&k[base + idx];
  }
  __syncthreads();
  const int qh = t >> 4, kh = t & 15;
  const unsigned* qb = (const unsigned*)&qs[0][0] + qh * 32;
  const unsigned* kb = (const unsigned*)&ks[0][0] + kh * 32;
  float e[8];
#pragma unroll
  for (int sl = 0; sl < 8; ++sl) {
    const unsigned* qrow = qb + sl * 512;
    const unsigned* krow = kb + sl * 512;
    float acc = 0.f;
#pragma unroll 8
    for (int p = 0; p < 32; ++p) {
      int pp = (p + kh) & 31;            // rotate to avoid LDS bank conflicts
      unsigned qp = qrow[pp];
      unsigned kp = krow[pp];
      acc += bflo(qp) * bflo(kp) + bfhi(qp) * bfhi(kp);
    }
    e[sl] = acc * 0.125f;                // / sqrt(64)
  }
  float* dst = E + ((size_t)((n * NH + qh) * NH + kh)) * S_LEN + s0;
#pragma unroll
  for (int sl = 0; sl < 8; ++sl) dst[sl] = e[sl];
}

// ---------------- per-row (1024 rows) max + 1/sum_exp over s=4096 ----------------
__global__ __launch_bounds__(256) void smstat_k(const float* __restrict__ E, float* __restrict__ mz) {
  __shared__ float red[8];
  const int t = threadIdx.x;
  const size_t r = blockIdx.x;
  const float* row = E + r * S_LEN;
  float vals[16];
  float m = -1e30f;
#pragma unroll
  for (int j = 0; j < 16; ++j) { vals[j] = row[t + j * 256]; m = fmaxf(m, vals[j]); }
#pragma unroll
  for (int off = 32; off > 0; off >>= 1) m = fmaxf(m, __shfl_down(m, off));
  if ((t & 63) == 0) red[t >> 6] = m;
  __syncthreads();
  m = fmaxf(fmaxf(red[0], red[1]), fmaxf(red[2], red[3]));
  float s = 0.f;
#pragma unroll
  for (int j = 0; j < 16; ++j) s += __expf(vals[j] - m);
#pragma unroll
  for (int off = 32; off > 0; off >>= 1) s += __shfl_down(s, off);
  if ((t & 63) == 0) red[4 + (t >> 6)] = s;
  __syncthreads();
  if (t == 0) {
    float Z = red[4] + red[5] + red[6] + red[7];
    mz[2 * r] = m;
    mz[2 * r + 1] = 1.f / Z;
  }
}

// ---------------- A[nq,s] = sum_kh softmax weight ----------------
__global__ __launch_bounds__(256) void asum_k(const float* __restrict__ E, const float* __restrict__ mz,
                                              float* __restrict__ A) {
  const int nq = blockIdx.y;                      // 0..63 = n*16+qh
  const int s = blockIdx.x * 256 + threadIdx.x;   // 0..4095
  float a = 0.f;
#pragma unroll
  for (int kh = 0; kh < NH; ++kh) {
    const int r = nq * NH + kh;
    a += __expf(E[(size_t)r * S_LEN + s] - mz[2 * r]) * mz[2 * r + 1];
  }
  A[(size_t)nq * S_LEN + s] = a;
}

// ---------------- Vs[n,s,d] = sum_h v[n,s,h*64+d] ----------------
__global__ __launch_bounds__(256) void vsum_k(const short* __restrict__ v, float* __restrict__ Vs) {
  const size_t i = (size_t)blockIdx.x * 256 + threadIdx.x;  // over 4*4096*64
  const size_t ns = i >> 6;
  const int d = (int)(i & 63);
  const short* p = v + ns * EMB + d;
  float a = 0.f;
#pragma unroll
  for (int h = 0; h < NH; ++h) a += bf2f(p[h * 64]);
  Vs[i] = a;
}

// ---------------- k/v output: pre[n,s,h*64+d] (bf16) -> out[n,h,s,d] (fp32) ----------------
__global__ __launch_bounds__(256) void kvout_k(const short* __restrict__ pre, float* __restrict__ out) {
  const size_t ns = blockIdx.x;
  const int n = (int)(ns >> 12), s = (int)(ns & 4095);
  const int t = threadIdx.x;
#pragma unroll
  for (int j = 0; j < 4; ++j) {
    int e = t + j * 256;
    int h = e >> 6, d = e & 63;
    out[(((size_t)n * NH + h) * S_LEN + s) * HD + d] = bf2f(pre[ns * EMB + e]);
  }
}

// ---------------- attn_in[n,s,e] = A[n, s/256, (s%256)*16 + e/64] * Vs[n, (s%256)*16+e/64, e%64] ----
__global__ __launch_bounds__(256) void attnin_k(const float* __restrict__ A, const float* __restrict__ Vs,
                                                short* __restrict__ out) {
  __shared__ float Ash[16];
  const int t = threadIdx.x;
  const size_t ns = blockIdx.x;
  const int n = (int)(ns >> 12), s = (int)(ns & 4095);
  const int qh = s >> 8;
  const int h0 = (s & 255) * 16;
  if (t < 16) Ash[t] = A[((size_t)(n * NH + qh)) * S_LEN + h0 + t];
  __syncthreads();
  const float* vsrc = Vs + ((size_t)n * S_LEN + h0) * HD;   // 1024 contiguous floats
#pragma unroll
  for (int j = 0; j < 4; ++j) {
    int e = t + j * 256;
    out[ns * EMB + e] = f2bf(Ash[e >> 6] * vsrc[e]);
  }
}

// ---------------- LayerNorm(a+b) * g + be ; optional bf16 copy ----------------
template<bool WBF>
__global__ __launch_bounds__(256) void ln_k(const float* __restrict__ a, const float* __restrict__ b,
                                            const float* __restrict__ g, const float* __restrict__ be,
                                            float* __restrict__ out, short* __restrict__ obf) {
  __shared__ float red[8];
  const int t = threadIdx.x;
  const size_t r = blockIdx.x;
  const float4 va = *(const float4*)(a + r * EMB + t * 4);
  const float4 vb = *(const float4*)(b + r * EMB + t * 4);
  const float v0 = va.x + vb.x, v1 = va.y + vb.y, v2 = va.z + vb.z, v3 = va.w + vb.w;
  float s = v0 + v1 + v2 + v3;
  float q = v0 * v0 + v1 * v1 + v2 * v2 + v3 * v3;
#pragma unroll
  for (int off = 32; off > 0; off >>= 1) { s += __shfl_down(s, off); q += __shfl_down(q, off); }
  if ((t & 63) == 0) { red[t >> 6] = s; red[4 + (t >> 6)] = q; }
  __syncthreads();
  const float S = red[0] + red[1] + red[2] + red[3];
  const float Q = red[4] + red[5] + red[6] + red[7];
  const float mu = S * (1.f / EMB);
  const float var = Q * (1.f / EMB) - mu * mu;
  const float rstd = rsqrtf(var + 1e-5f);
  const float4 vg = *(const float4*)(g + t * 4);
  const float4 ve = *(const float4*)(be + t * 4);
  const float y0 = (v0 - mu) * rstd * vg.x + ve.x;
  const float y1 = (v1 - mu) * rstd * vg.y + ve.y;
  const float y2 = (v2 - mu) * rstd * vg.z + ve.z;
  const float y3 = (v3 - mu) * rstd * vg.w + ve.w;
  float4 yo; yo.x = y0; yo.y = y1; yo.z = y2; yo.w = y3;
  *(float4*)(out + r * EMB + t * 4) = yo;
  if (WBF) {
    short4 o; o.x = f2bf(y0); o.y = f2bf(y1); o.z = f2bf(y2); o.w = f2bf(y3);
    *(short4*)(obf + r * EMB + t * 4) = o;
  }
}

extern "C" void kernel_launch(void* const* d_in, const int* in_sizes, int n_in,
                              void* d_out, int out_size, void* d_ws, size_t ws_size,
                              hipStream_t stream) {
  const float* x   = (const float*)d_in[0];
  const float* Wq  = (const float*)d_in[1];
  const float* Wk  = (const float*)d_in[2];
  const float* Wv  = (const float*)d_in[3];
  const float* Wo  = (const float*)d_in[4];
  const float* bo  = (const float*)d_in[5];
  const float* W1  = (const float*)d_in[6];
  const float* b1  = (const float*)d_in[7];
  const float* W2  = (const float*)d_in[8];
  const float* b2  = (const float*)d_in[9];
  const float* g1  = (const float*)d_in[10];
  const float* be1 = (const float*)d_in[11];
  const float* g2  = (const float*)d_in[12];
  const float* be2 = (const float*)d_in[13];

  float* y    = (float*)d_out;                       // [4,4096,1024]
  float* kout = y + (size_t)MROWS * EMB;             // [4,16,4096,64]
  float* vout = kout + (size_t)MROWS * EMB;

  constexpr size_t MB = 1ull << 20;
  char* ws = (char*)d_ws;
  short* WqT     = (short*)(ws + 0 * MB);    // 2 MB each
  short* WkT     = (short*)(ws + 2 * MB);
  short* WvT     = (short*)(ws + 4 * MB);
  short* WoT     = (short*)(ws + 6 * MB);
  short* W1T     = (short*)(ws + 8 * MB);    // 8 MB
  short* W2T     = (short*)(ws + 16 * MB);   // 8 MB
  short* xbf     = (short*)(ws + 24 * MB);   // 32 MB
  short* qpre    = (short*)(ws + 56 * MB);   // 32 MB
  short* kpre    = (short*)(ws + 88 * MB);   // 32 MB
  short* vpre    = (short*)(ws + 120 * MB);  // 32 MB
  float* energy  = (float*)(ws + 152 * MB);  // 16 MB
  float* mz      = (float*)(ws + 168 * MB);  // 8 KB
  float* Avec    = (float*)(ws + 169 * MB);  // 1 MB
  float* Vsb     = (float*)(ws + 170 * MB);  // 4 MB
  short* attn_in = (short*)(ws + 174 * MB);  // 32 MB
  float* attn_out= (float*)(ws + 206 * MB);  // 64 MB
  float* hbuf    = (float*)(ws + 270 * MB);  // 64 MB
  short* hbf     = (short*)(ws + 334 * MB);  // 32 MB
  short* ff1     = (short*)(ws + 24 * MB);   // 128 MB, reuses [24,152) (xbf/q/k/v dead)
  float* ff2     = (float*)(ws + 174 * MB);  // 64 MB, reuses [174,238) (attn_in/attn_out dead)

  // 1) casts / transposes
  cvtx_k<<<8192, 256, 0, stream>>>(x, xbf);
  transpose_cvt_k<<<dim3(32, 32),  dim3(32, 8), 0, stream>>>(Wq, WqT, EMB, EMB);
  transpose_cvt_k<<<dim3(32, 32),  dim3(32, 8), 0, stream>>>(Wk, WkT, EMB, EMB);
  transpose_cvt_k<<<dim3(32, 32),  dim3(32, 8), 0, stream>>>(Wv, WvT, EMB, EMB);
  transpose_cvt_k<<<dim3(32, 32),  dim3(32, 8), 0, stream>>>(Wo, WoT, EMB, EMB);
  transpose_cvt_k<<<dim3(128, 32), dim3(32, 8), 0, stream>>>(W1, W1T, EMB, DFF);
  transpose_cvt_k<<<dim3(32, 128), dim3(32, 8), 0, stream>>>(W2, W2T, DFF, EMB);

  // 2) projections (grid = (M/256)*(N/256), 512 threads)
  gemm2<true, false, false><<<256, 512, 0, stream>>>(xbf, WqT, nullptr, qpre, EMB, EMB, 2);
  gemm2<true, false, false><<<256, 512, 0, stream>>>(xbf, WkT, nullptr, kpre, EMB, EMB, 2);
  gemm2<true, false, false><<<256, 512, 0, stream>>>(xbf, WvT, nullptr, vpre, EMB, EMB, 2);

  // 3) factorized "attention"
  energy_k<<<2048, 256, 0, stream>>>(qpre, kpre, energy);
  smstat_k<<<1024, 256, 0, stream>>>(energy, mz);
  asum_k<<<dim3(16, 64), 256, 0, stream>>>(energy, mz, Avec);
  vsum_k<<<4096, 256, 0, stream>>>(vpre, Vsb);
  kvout_k<<<16384, 256, 0, stream>>>(kpre, kout);
  kvout_k<<<16384, 256, 0, stream>>>(vpre, vout);
  attnin_k<<<16384, 256, 0, stream>>>(Avec, Vsb, attn_in);

  // 4) output projection + LN1
  gemm2<false, false, true><<<256, 512, 0, stream>>>(attn_in, WoT, bo, attn_out, EMB, EMB, 2);
  ln_k<true><<<16384, 256, 0, stream>>>(attn_out, x, g1, be1, hbuf, hbf);

  // 5) FFN + LN2
  gemm2<true, true, true><<<1024, 512, 0, stream>>>(hbf, W1T, b1, ff1, DFF, EMB, 4);
  gemm2<false, false, true><<<256, 512, 0, stream>>>(ff1, W2T, b2, ff2, EMB, DFF, 2);
  ln_k<false><<<16384, 256, 0, stream>>>(ff2, hbuf, g2, be2, y, nullptr);
}

// Round 5
// 809.453 us; speedup vs baseline: 1.4180x; 1.0977x over previous
//
#include <hip/hip_runtime.h>

// Transformer block, MI355X. Attention factorizes to A[n,qh,s]*Vs[n,s,d].
// Round 5: (a) GEMM de-convoyed: counted post-MFMA lgkm waits, 1 barrier/phase,
// B fully front-loaded, last-iteration peeled (no redundant restage);
// (b) fusions: kvout into k/v epilogues, residual+bias into Wo/W2 epilogues (bf16),
// single-input bf16 LayerNorms.

#define S_LEN 4096
#define EMB   1024
#define NBATCH 4
#define NH    16
#define HD    64
#define DFF   4096
#define MROWS (NBATCH * S_LEN)  // 16384

typedef __attribute__((ext_vector_type(8))) short s16x8;
typedef __attribute__((ext_vector_type(4))) float f32x4;

__device__ __forceinline__ float uas_f(unsigned u) { union { unsigned u; float f; } c; c.u = u; return c.f; }
__device__ __forceinline__ unsigned fas_u(float f) { union { float f; unsigned u; } c; c.f = f; return c.u; }
__device__ __forceinline__ short f2bf(float f) {
  unsigned u = fas_u(f);
  u += 0x7fffu + ((u >> 16) & 1u);           // RNE
  return (short)(unsigned short)(u >> 16);
}
__device__ __forceinline__ float bf2f(short h) { return uas_f(((unsigned)(unsigned short)h) << 16); }
__device__ __forceinline__ float bflo(unsigned pk) { return uas_f(pk << 16); }
__device__ __forceinline__ float bfhi(unsigned pk) { return uas_f(pk & 0xffff0000u); }

__device__ __forceinline__ void gld16(const short* g, short* l) {
  __builtin_amdgcn_global_load_lds((const __attribute__((address_space(1))) void*)g,
                                   (__attribute__((address_space(3))) void*)l, 16, 0, 0);
}

// ================= 256x256 GEMM, 8 phases / 2 K-tiles, 1 barrier per phase =================
// C[M,N] = A[M,K] @ BT[N,K]^T. 512 thr = 8 waves (2M x 4N), per-wave 128x64 out.
// BK=64/K-tile. LDS 128KB: 2 bufs x (A 32K + B 32K). Subtile 16 rows x 32 k (1024B),
// st_16x32 swizzle via pre-permuted global source. Plain C++ ds-loads -> compiler emits
// fine-grained counted lgkm waits per MFMA (no blanket pre-MFMA drain = LDS/MFMA overlap).
// Sync chains (all verified): reads of phase p are drained by end-of-phase LGKM before its
// BAR; STG of a region issues only after the BAR following its readers' drain; VMC8 before
// the BAR preceding the other buffer's reads. vmcnt never 0 in steady state.
#define BAR()   __builtin_amdgcn_s_barrier()
#define LGKM0() asm volatile("s_waitcnt lgkmcnt(0)" ::: "memory")
#define LGKM4() asm volatile("s_waitcnt lgkmcnt(4)" ::: "memory")
#define VMC8()  asm volatile("s_waitcnt vmcnt(8)" ::: "memory")
#define VMC0()  asm volatile("s_waitcnt vmcnt(0)" ::: "memory")

#define LOADA(BUFOFF, QH) do { \
  _Pragma("unroll") for (int mi = 0; mi < 4; ++mi) { \
    aR[mi][0] = *(const s16x8*)(aB + (BUFOFF) + (((QH)*8 + mi*2 + 0) << 10)); \
    aR[mi][1] = *(const s16x8*)(aB + (BUFOFF) + (((QH)*8 + mi*2 + 1) << 10)); } } while (0)

#define LOADB(BUFOFF, NH_) do { \
  _Pragma("unroll") for (int nf = 0; nf < 2; ++nf) { \
    bR[NH_][nf][0] = *(const s16x8*)(bB + (BUFOFF) + ((((NH_)*2 + nf)*2 + 0) << 10)); \
    bR[NH_][nf][1] = *(const s16x8*)(bB + (BUFOFF) + ((((NH_)*2 + nf)*2 + 1) << 10)); } } while (0)

#define MFMA16(QH, NH_) do { \
  _Pragma("unroll") for (int mi = 0; mi < 4; ++mi) \
  _Pragma("unroll") for (int nf = 0; nf < 2; ++nf) { \
    acc[(QH)*4+mi][(NH_)*2+nf] = __builtin_amdgcn_mfma_f32_16x16x32_bf16(aR[mi][0], bR[NH_][nf][0], acc[(QH)*4+mi][(NH_)*2+nf], 0, 0, 0); \
    acc[(QH)*4+mi][(NH_)*2+nf] = __builtin_amdgcn_mfma_f32_16x16x32_bf16(aR[mi][1], bR[NH_][nf][1], acc[(QH)*4+mi][(NH_)*2+nf], 0, 0, 0); } } while (0)

#define STG(PTR, OPOFF, BUFOFF, H, KOFF) do { \
  const short* _s = (PTR) + (KOFF); \
  char* _d = ldsc + (BUFOFF) + (OPOFF) + (H)*16384 + wq; \
  gld16(_s, (short*)_d); gld16(_s + 32, (short*)(_d + 1024)); } while (0)

#define PRIO1() __builtin_amdgcn_s_setprio(1)
#define PRIO0() __builtin_amdgcn_s_setprio(0)

// One K-tile (4 phases). DOSTG: restage this buffer's next tile at KR. VMCT at phase 3.
#define KSTEP(BUF, KR, DOSTG, VMCT) do { \
  /* P0: all reads for this tile's B + A-quadrant 0 */ \
  LOADA(BUF, 0); LOADB(BUF, 0); LOADB(BUF, 1); \
  PRIO1(); MFMA16(0, 0); PRIO0(); LGKM4(); BAR(); \
  /* P1: pure MFMA (B1 regs land under P0 tail service) */ \
  PRIO1(); MFMA16(0, 1); PRIO0(); LGKM0(); BAR(); \
  /* P2: A-quadrant 1 reads; restage B (B LDS reads drained end-P1) */ \
  LOADA(BUF, 1); \
  if (DOSTG) { STG(pB0, 32768, BUF, 0, KR); STG(pB1, 32768, BUF, 1, KR); } \
  PRIO1(); MFMA16(1, 1); PRIO0(); LGKM0(); BAR(); \
  /* P3: pure MFMA; restage A (A reads drained end-P2); drain other buf's tile */ \
  if (DOSTG) { STG(pA0, 0, BUF, 0, KR); STG(pA1, 0, BUF, 1, KR); } \
  PRIO1(); MFMA16(1, 0); PRIO0(); LGKM0(); VMCT; BAR(); \
} while (0)

// CM: 0=fp32 C, 1=bf16 C. RES: 0 none, 1 fp32 resid, 2 bf16 resid. KV: also fp32 [n,h,s,d] copy.
template<int CM, bool RELU, bool BIAS, bool KV, int RES>
__global__ __launch_bounds__(512, 2) void gemm2(const short* __restrict__ A,
                                                const short* __restrict__ BT,
                                                const float* __restrict__ bias,
                                                void* __restrict__ Cp,
                                                float* __restrict__ kvp,
                                                const float* __restrict__ resf,
                                                const short* __restrict__ resb,
                                                int N, int K, int lgx) {
  __shared__ __align__(16) char lds[131072];
  char* ldsc = &lds[0];
  const int t = threadIdx.x;
  const int lane = t & 63;
  const int wave = t >> 6;
  const int wr = wave >> 2, wc = wave & 3;

  // T1: XCD-aware block swizzle (nwg % 8 == 0 -> bijective)
  const int nwg = gridDim.x;
  const int wg = blockIdx.x;
  const int sid = (wg & 7) * (nwg >> 3) + (wg >> 3);
  const int bx = sid & ((1 << lgx) - 1);
  const int by = sid >> lgx;
  const size_t m0 = (size_t)by * 256, n0 = (size_t)bx * 256;

  // staging addresses (source pre-permuted for st_16x32 swizzle; LDS dest linear)
  const int uc = lane ^ (((lane >> 5) & 1) << 1);
  const size_t arow = m0 + wave * 16 + (uc >> 2);
  const size_t brow = n0 + wave * 16 + (uc >> 2);
  const int csub = (uc & 3) << 3;
  const short* pA0 = A  + arow * K + csub;
  const short* pA1 = A  + (arow + 128) * K + csub;
  const short* pB0 = BT + brow * K + csub;
  const short* pB1 = BT + (brow + 128) * K + csub;
  const int wq = wave * 2048 + lane * 16;

  // ds_read bases (st_16x32 swizzle XOR on read address)
  int ulane = ((lane & 15) << 6) | ((lane >> 4) << 4);
  ulane ^= ((lane >> 3) & 1) << 5;
  const char* aB = ldsc + (wr << 14) + ulane;
  const char* bB = ldsc + 32768 + (wc << 13) + ulane;

  s16x8 aR[4][2];
  s16x8 bR[2][2][2];
  f32x4 acc[8][4] = {};

  // prologue: stage tile0 -> buf0, tile1 -> buf1; complete tile0 (16-8=8)
  STG(pA0, 0,     0, 0, 0);       STG(pB0, 32768, 0, 0, 0);
  STG(pB1, 32768, 0, 1, 0);       STG(pA1, 0,     0, 1, 0);
  STG(pA0, 0,     65536, 0, 64);  STG(pB0, 32768, 65536, 0, 64);
  STG(pB1, 32768, 65536, 1, 64);  STG(pA1, 0,     65536, 1, 64);
  VMC8();
  BAR();

  const int niter = K >> 7;              // 2 K-tiles per iteration
  for (int it = 0; it < niter - 1; ++it) {
    const int kb = it << 7;
    KSTEP(0,     kb + 128, 1, VMC8());   // consume [kb,kb+64), restage buf0 <- kb+128
    KSTEP(65536, kb + 192, 1, VMC8());   // consume [kb+64,kb+128), restage buf1 <- kb+192
  }
  // peeled tail: no restage; drain buf1's tile before reading it
  KSTEP(0,     0, 0, VMC0());
  KSTEP(65536, 0, 0, ((void)0));

  // epilogue: C/D layout col=lane&15, row=(lane>>4)*4+reg
  const int r0 = (lane >> 4) << 2;
  const int c0 = lane & 15;
#pragma unroll
  for (int i = 0; i < 8; ++i) {
#pragma unroll
    for (int j = 0; j < 4; ++j) {
      const size_t row = m0 + (size_t)(wr * 128 + i * 16 + r0);
      const size_t col = n0 + (size_t)(wc * 64 + j * 16 + c0);
      float bv = 0.f;
      if (BIAS) bv = bias[col];
#pragma unroll
      for (int r = 0; r < 4; ++r) {
        float v = acc[i][j][r] + bv;
        if (RES == 1) v += resf[(row + r) * N + col];
        if (RES == 2) v += bf2f(resb[(row + r) * N + col]);
        if (RELU) v = fmaxf(v, 0.f);
        if (CM) ((short*)Cp)[(row + r) * N + col] = f2bf(v);
        else    ((float*)Cp)[(row + r) * N + col] = v;
        if (KV) {
          const size_t rr = row + r;
          const int n = (int)(rr >> 12), s = (int)(rr & 4095);
          const int h = (int)(col >> 6), d = (int)(col & 63);
          kvp[(((size_t)n * NH + h) * S_LEN + s) * HD + d] = v;
        }
      }
    }
  }
}

// ---------------- fp32 -> bf16 convert (x) ----------------
__global__ __launch_bounds__(256) void cvtx_k(const float* __restrict__ in, short* __restrict__ out) {
  const size_t i = ((size_t)blockIdx.x * 256 + threadIdx.x) * 8;
  const float4 a = *(const float4*)(in + i);
  const float4 b = *(const float4*)(in + i + 4);
  s16x8 o;
  o[0] = f2bf(a.x); o[1] = f2bf(a.y); o[2] = f2bf(a.z); o[3] = f2bf(a.w);
  o[4] = f2bf(b.x); o[5] = f2bf(b.y); o[6] = f2bf(b.z); o[7] = f2bf(b.w);
  *(s16x8*)(out + i) = o;
}

// ---------------- W[K,N] fp32 -> W^T[N,K] bf16 ----------------
__global__ void transpose_cvt_k(const float* __restrict__ W, short* __restrict__ WT, int K, int N) {
  __shared__ float tile[32][33];
  const int tx = threadIdx.x, ty = threadIdx.y;  // (32,8)
  const int n0 = blockIdx.x * 32, k0 = blockIdx.y * 32;
#pragma unroll
  for (int i = 0; i < 32; i += 8)
    tile[ty + i][tx] = W[(size_t)(k0 + ty + i) * N + n0 + tx];
  __syncthreads();
#pragma unroll
  for (int i = 0; i < 32; i += 8)
    WT[(size_t)(n0 + ty + i) * K + k0 + tx] = f2bf(tile[tx][ty + i]);
}

// ---------------- energy[n,qh,kh,s] = (1/8) sum_d q[n,s,qh*64+d]*k[n,s,kh*64+d] ----------------
__global__ __launch_bounds__(256) void energy_k(const short* __restrict__ q,
                                                const short* __restrict__ k,
                                                float* __restrict__ E) {
  __shared__ short qs[8][1024];
  __shared__ short ks[8][1024];
  const int t = threadIdx.x;
  const int blk = blockIdx.x;
  const int n = blk >> 9;
  const int s0 = (blk & 511) << 3;
  const size_t base = ((size_t)n * S_LEN + s0) * EMB;
#pragma unroll
  for (int i = 0; i < 4; ++i) {
    int idx = (t + i * 256) * 8;
    *(s16x8*)&qs[0][idx] = *(const s16x8*)&q[base + idx];
    *(s16x8*)&ks[0][idx] = *(const s16x8*)&k[base + idx];
  }
  __syncthreads();
  const int qh = t >> 4, kh = t & 15;
  const unsigned* qb = (const unsigned*)&qs[0][0] + qh * 32;
  const unsigned* kb = (const unsigned*)&ks[0][0] + kh * 32;
  float e[8];
#pragma unroll
  for (int sl = 0; sl < 8; ++sl) {
    const unsigned* qrow = qb + sl * 512;
    const unsigned* krow = kb + sl * 512;
    float acc = 0.f;
#pragma unroll 8
    for (int p = 0; p < 32; ++p) {
      int pp = (p + kh) & 31;
      unsigned qp = qrow[pp];
      unsigned kp = krow[pp];
      acc += bflo(qp) * bflo(kp) + bfhi(qp) * bfhi(kp);
    }
    e[sl] = acc * 0.125f;
  }
  float* dst = E + ((size_t)((n * NH + qh) * NH + kh)) * S_LEN + s0;
#pragma unroll
  for (int sl = 0; sl < 8; ++sl) dst[sl] = e[sl];
}

// ---------------- per-row (1024 rows) max + 1/sum_exp over s=4096 ----------------
__global__ __launch_bounds__(256) void smstat_k(const float* __restrict__ E, float* __restrict__ mz) {
  __shared__ float red[8];
  const int t = threadIdx.x;
  const size_t r = blockIdx.x;
  const float* row = E + r * S_LEN;
  float vals[16];
  float m = -1e30f;
#pragma unroll
  for (int j = 0; j < 16; ++j) { vals[j] = row[t + j * 256]; m = fmaxf(m, vals[j]); }
#pragma unroll
  for (int off = 32; off > 0; off >>= 1) m = fmaxf(m, __shfl_down(m, off));
  if ((t & 63) == 0) red[t >> 6] = m;
  __syncthreads();
  m = fmaxf(fmaxf(red[0], red[1]), fmaxf(red[2], red[3]));
  float s = 0.f;
#pragma unroll
  for (int j = 0; j < 16; ++j) s += __expf(vals[j] - m);
#pragma unroll
  for (int off = 32; off > 0; off >>= 1) s += __shfl_down(s, off);
  if ((t & 63) == 0) red[4 + (t >> 6)] = s;
  __syncthreads();
  if (t == 0) {
    float Z = red[4] + red[5] + red[6] + red[7];
    mz[2 * r] = m;
    mz[2 * r + 1] = 1.f / Z;
  }
}

// ---------------- A[nq,s] = sum_kh softmax weight ----------------
__global__ __launch_bounds__(256) void asum_k(const float* __restrict__ E, const float* __restrict__ mz,
                                              float* __restrict__ A) {
  const int nq = blockIdx.y;
  const int s = blockIdx.x * 256 + threadIdx.x;
  float a = 0.f;
#pragma unroll
  for (int kh = 0; kh < NH; ++kh) {
    const int r = nq * NH + kh;
    a += __expf(E[(size_t)r * S_LEN + s] - mz[2 * r]) * mz[2 * r + 1];
  }
  A[(size_t)nq * S_LEN + s] = a;
}

// ---------------- Vs[n,s,d] = sum_h v[n,s,h*64+d] ----------------
__global__ __launch_bounds__(256) void vsum_k(const short* __restrict__ v, float* __restrict__ Vs) {
  const size_t i = (size_t)blockIdx.x * 256 + threadIdx.x;
  const size_t ns = i >> 6;
  const int d = (int)(i & 63);
  const short* p = v + ns * EMB + d;
  float a = 0.f;
#pragma unroll
  for (int h = 0; h < NH; ++h) a += bf2f(p[h * 64]);
  Vs[i] = a;
}

// ---------------- attn_in[n,s,e] = A[n, s/256, (s%256)*16 + e/64] * Vs[n, (s%256)*16+e/64, e%64] ----
__global__ __launch_bounds__(256) void attnin_k(const float* __restrict__ A, const float* __restrict__ Vs,
                                                short* __restrict__ out) {
  __shared__ float Ash[16];
  const int t = threadIdx.x;
  const size_t ns = blockIdx.x;
  const int n = (int)(ns >> 12), s = (int)(ns & 4095);
  const int qh = s >> 8;
  const int h0 = (s & 255) * 16;
  if (t < 16) Ash[t] = A[((size_t)(n * NH + qh)) * S_LEN + h0 + t];
  __syncthreads();
  const float* vsrc = Vs + ((size_t)n * S_LEN + h0) * HD;
#pragma unroll
  for (int j = 0; j < 4; ++j) {
    int e = t + j * 256;
    out[ns * EMB + e] = f2bf(Ash[e >> 6] * vsrc[e]);
  }
}

// ---------------- LayerNorm over a single bf16 row; out fp32 (y) or bf16 (h) ----------------
template<bool OBF>
__global__ __launch_bounds__(256) void ln_s(const short* __restrict__ in,
                                            const float* __restrict__ g, const float* __restrict__ be,
                                            void* __restrict__ outp) {
  __shared__ float red[8];
  const int t = threadIdx.x;
  const size_t r = blockIdx.x;
  const short4 a = *(const short4*)(in + r * EMB + t * 4);
  const float v0 = bf2f(a.x), v1 = bf2f(a.y), v2 = bf2f(a.z), v3 = bf2f(a.w);
  float s = v0 + v1 + v2 + v3;
  float q = v0 * v0 + v1 * v1 + v2 * v2 + v3 * v3;
#pragma unroll
  for (int off = 32; off > 0; off >>= 1) { s += __shfl_down(s, off); q += __shfl_down(q, off); }
  if ((t & 63) == 0) { red[t >> 6] = s; red[4 + (t >> 6)] = q; }
  __syncthreads();
  const float S = red[0] + red[1] + red[2] + red[3];
  const float Q = red[4] + red[5] + red[6] + red[7];
  const float mu = S * (1.f / EMB);
  const float var = Q * (1.f / EMB) - mu * mu;
  const float rstd = rsqrtf(var + 1e-5f);
  const float4 vg = *(const float4*)(g + t * 4);
  const float4 ve = *(const float4*)(be + t * 4);
  const float y0 = (v0 - mu) * rstd * vg.x + ve.x;
  const float y1 = (v1 - mu) * rstd * vg.y + ve.y;
  const float y2 = (v2 - mu) * rstd * vg.z + ve.z;
  const float y3 = (v3 - mu) * rstd * vg.w + ve.w;
  if (OBF) {
    short4 o; o.x = f2bf(y0); o.y = f2bf(y1); o.z = f2bf(y2); o.w = f2bf(y3);
    *(short4*)((short*)outp + r * EMB + t * 4) = o;
  } else {
    float4 yo; yo.x = y0; yo.y = y1; yo.z = y2; yo.w = y3;
    *(float4*)((float*)outp + r * EMB + t * 4) = yo;
  }
}

extern "C" void kernel_launch(void* const* d_in, const int* in_sizes, int n_in,
                              void* d_out, int out_size, void* d_ws, size_t ws_size,
                              hipStream_t stream) {
  const float* x   = (const float*)d_in[0];
  const float* Wq  = (const float*)d_in[1];
  const float* Wk  = (const float*)d_in[2];
  const float* Wv  = (const float*)d_in[3];
  const float* Wo  = (const float*)d_in[4];
  const float* bo  = (const float*)d_in[5];
  const float* W1  = (const float*)d_in[6];
  const float* b1  = (const float*)d_in[7];
  const float* W2  = (const float*)d_in[8];
  const float* b2  = (const float*)d_in[9];
  const float* g1  = (const float*)d_in[10];
  const float* be1 = (const float*)d_in[11];
  const float* g2  = (const float*)d_in[12];
  const float* be2 = (const float*)d_in[13];

  float* y    = (float*)d_out;                       // [4,4096,1024]
  float* kout = y + (size_t)MROWS * EMB;             // [4,16,4096,64]
  float* vout = kout + (size_t)MROWS * EMB;

  constexpr size_t MB = 1ull << 20;
  char* ws = (char*)d_ws;
  short* WqT     = (short*)(ws + 0 * MB);
  short* WkT     = (short*)(ws + 2 * MB);
  short* WvT     = (short*)(ws + 4 * MB);
  short* WoT     = (short*)(ws + 6 * MB);
  short* W1T     = (short*)(ws + 8 * MB);    // 8 MB
  short* W2T     = (short*)(ws + 16 * MB);   // 8 MB
  short* xbf     = (short*)(ws + 24 * MB);   // 32 MB
  short* qpre    = (short*)(ws + 56 * MB);   // 32 MB
  short* kpre    = (short*)(ws + 88 * MB);   // 32 MB
  short* vpre    = (short*)(ws + 120 * MB);  // 32 MB
  float* energy  = (float*)(ws + 152 * MB);  // 16 MB
  float* mz      = (float*)(ws + 168 * MB);  // 8 KB
  float* Avec    = (float*)(ws + 169 * MB);  // 1 MB
  float* Vsb     = (float*)(ws + 170 * MB);  // 4 MB
  short* attn_in = (short*)(ws + 174 * MB);  // 32 MB
  short* attn_res= (short*)(ws + 206 * MB);  // 32 MB (bf16: Wo out + bo + x)
  short* hbf     = (short*)(ws + 334 * MB);  // 32 MB (LN1 out, bf16)
  short* ff1     = (short*)(ws + 24 * MB);   // 128 MB, reuses [24,152)
  short* ff2res  = (short*)(ws + 174 * MB);  // 32 MB (bf16: W2 out + b2 + h), reuses attn_in

  // 1) casts / transposes
  cvtx_k<<<8192, 256, 0, stream>>>(x, xbf);
  transpose_cvt_k<<<dim3(32, 32),  dim3(32, 8), 0, stream>>>(Wq, WqT, EMB, EMB);
  transpose_cvt_k<<<dim3(32, 32),  dim3(32, 8), 0, stream>>>(Wk, WkT, EMB, EMB);
  transpose_cvt_k<<<dim3(32, 32),  dim3(32, 8), 0, stream>>>(Wv, WvT, EMB, EMB);
  transpose_cvt_k<<<dim3(32, 32),  dim3(32, 8), 0, stream>>>(Wo, WoT, EMB, EMB);
  transpose_cvt_k<<<dim3(128, 32), dim3(32, 8), 0, stream>>>(W1, W1T, EMB, DFF);
  transpose_cvt_k<<<dim3(32, 128), dim3(32, 8), 0, stream>>>(W2, W2T, DFF, EMB);

  // 2) projections; k/v fuse the fp32 [n,h,s,d] output copy
  gemm2<1, false, false, false, 0><<<256, 512, 0, stream>>>(xbf, WqT, nullptr, qpre, nullptr, nullptr, nullptr, EMB, EMB, 2);
  gemm2<1, false, false, true,  0><<<256, 512, 0, stream>>>(xbf, WkT, nullptr, kpre, kout,    nullptr, nullptr, EMB, EMB, 2);
  gemm2<1, false, false, true,  0><<<256, 512, 0, stream>>>(xbf, WvT, nullptr, vpre, vout,    nullptr, nullptr, EMB, EMB, 2);

  // 3) factorized "attention"
  energy_k<<<2048, 256, 0, stream>>>(qpre, kpre, energy);
  smstat_k<<<1024, 256, 0, stream>>>(energy, mz);
  asum_k<<<dim3(16, 64), 256, 0, stream>>>(energy, mz, Avec);
  vsum_k<<<4096, 256, 0, stream>>>(vpre, Vsb);
  attnin_k<<<16384, 256, 0, stream>>>(Avec, Vsb, attn_in);

  // 4) output projection (+bo +x, bf16) + LN1 (bf16 in -> bf16 h)
  gemm2<1, false, true, false, 1><<<256, 512, 0, stream>>>(attn_in, WoT, bo, attn_res, nullptr, x, nullptr, EMB, EMB, 2);
  ln_s<true><<<16384, 256, 0, stream>>>(attn_res, g1, be1, hbf);

  // 5) FFN (+b2 +h fused) + LN2 -> y
  gemm2<1, true,  true, false, 0><<<1024, 512, 0, stream>>>(hbf, W1T, b1, ff1, nullptr, nullptr, nullptr, DFF, EMB, 4);
  gemm2<1, false, true, false, 2><<<256, 512, 0, stream>>>(ff1, W2T, b2, ff2res, nullptr, nullptr, hbf, EMB, DFF, 2);
  ln_s<false><<<16384, 256, 0, stream>>>(ff2res, g2, be2, y);
}